// Round 1
// baseline (122.176 us; speedup 1.0000x reference)
//
#include <hip/hip_runtime.h>
#include <math.h>

// Problem constants (from reference: FX=FY=48, CX=48, CY=36, H=72, W=96)
#define HH 72
#define WW 96
#define NPIX 6912          // H*W
#define CCH 16             // feature channels
#define TSZ 256            // tile size (rows and cols per block)
#define NBLK 27            // NPIX / TSZ

// Workspace layout (floats):
//  f1n  : [16][N]   at 0        (c-major normalized feature1)
//  f2n  : [16][N]   at 16*N     (c-major normalized feature2)
//  aux1 : [N][4]    at 32*N     {x1,y1,z1,|p1|^2}
//  col2 : [N][8]    at 36*N     {x2t,y2t,z2t,|p2t|^2, x2n,y2n,z2n,|p2n|^2}
// total 44*N floats = 1.19 MB

__device__ __forceinline__ float block_reduce_256(float v, float* smem4) {
    #pragma unroll
    for (int o = 32; o > 0; o >>= 1) v += __shfl_down(v, o, 64);
    int lane = threadIdx.x & 63;
    int w = threadIdx.x >> 6;
    if (lane == 0) smem4[w] = v;
    __syncthreads();
    float r = 0.0f;
    if (threadIdx.x == 0) r = smem4[0] + smem4[1] + smem4[2] + smem4[3];
    return r;
}

__global__ __launch_bounds__(256)
void preproc_kernel(const float* __restrict__ f1, const float* __restrict__ f2,
                    const float* __restrict__ d1, const float* __restrict__ d2,
                    const float* __restrict__ pose, const float* __restrict__ pnz,
                    float* __restrict__ ws, float* __restrict__ out) {
    __shared__ float smem4[4];
    const int i = blockIdx.x * 256 + threadIdx.x;

    float* f1n  = ws;
    float* f2n  = ws + 16 * NPIX;
    float* aux1 = ws + 32 * NPIX;
    float* col2 = ws + 36 * NPIX;

    // pose rows 0..2 (uniform loads -> scalarized)
    float P[12];
    #pragma unroll
    for (int k = 0; k < 12; k++) P[k] = pose[k];
    // noisy pose = pose1_2 @ pose_noise, rows 0..2
    float Q[12];
    #pragma unroll
    for (int r = 0; r < 3; r++) {
        #pragma unroll
        for (int c = 0; c < 4; c++) {
            float s = 0.0f;
            #pragma unroll
            for (int k = 0; k < 4; k++) s = fmaf(pose[r * 4 + k], pnz[k * 4 + c], s);
            Q[r * 4 + c] = s;
        }
    }

    // back-projection ray: yz1 = (1, (u-48)/48, (v-36)/48)
    const float inv48 = 1.0f / 48.0f;
    const int u = i % WW;
    const int v = i / WW;
    const float y0 = 1.0f;
    const float y1 = fmaf((float)u, inv48, -1.0f);
    const float y2 = fmaf((float)v, inv48, -0.75f);

    // point cloud 1
    const float dep1 = d1[i];
    const float p1x = y0 * dep1, p1y = y1 * dep1, p1z = y2 * dep1;
    const float n1 = p1x * p1x + p1y * p1y + p1z * p1z;
    aux1[i * 4 + 0] = p1x;
    aux1[i * 4 + 1] = p1y;
    aux1[i * 4 + 2] = p1z;
    aux1[i * 4 + 3] = n1;

    // point cloud 2, transformed by pose and noisy pose
    const float dep2 = d2[i];
    const float a = y0 * dep2, b = y1 * dep2, c = y2 * dep2;
    float t0 = P[0] * a + P[1] * b + P[2]  * c + P[3];
    float t1 = P[4] * a + P[5] * b + P[6]  * c + P[7];
    float t2 = P[8] * a + P[9] * b + P[10] * c + P[11];
    float q0 = Q[0] * a + Q[1] * b + Q[2]  * c + Q[3];
    float q1 = Q[4] * a + Q[5] * b + Q[6]  * c + Q[7];
    float q2 = Q[8] * a + Q[9] * b + Q[10] * c + Q[11];
    col2[i * 8 + 0] = t0;
    col2[i * 8 + 1] = t1;
    col2[i * 8 + 2] = t2;
    col2[i * 8 + 3] = t0 * t0 + t1 * t1 + t2 * t2;
    col2[i * 8 + 4] = q0;
    col2[i * 8 + 5] = q1;
    col2[i * 8 + 6] = q2;
    col2[i * 8 + 7] = q0 * q0 + q1 * q1 + q2 * q2;

    // feature normalization (L2 over channels) + norm sums
    float v1[CCH], v2[CCH];
    float s1 = 0.0f, s2 = 0.0f;
    #pragma unroll
    for (int cc = 0; cc < CCH; cc++) {
        v1[cc] = f1[cc * NPIX + i];
        v2[cc] = f2[cc * NPIX + i];
        s1 = fmaf(v1[cc], v1[cc], s1);
        s2 = fmaf(v2[cc], v2[cc], s2);
    }
    const float nrm1 = sqrtf(s1);
    const float nrm2 = sqrtf(s2);
    const float r1 = 1.0f / (nrm1 + 1e-8f);
    const float r2 = 1.0f / (nrm2 + 1e-8f);
    #pragma unroll
    for (int cc = 0; cc < CCH; cc++) {
        f1n[cc * NPIX + i] = v1[cc] * r1;
        f2n[cc * NPIX + i] = v2[cc] * r2;
    }

    float tot = block_reduce_256(nrm1 + nrm2, smem4);
    if (threadIdx.x == 0) atomicAdd(out + 2, 100.0f * tot);
}

__global__ __launch_bounds__(256)
void pair_loss_kernel(const float* __restrict__ ws, float* __restrict__ out) {
    // tile: 256 rows x {f1n[0..15], p1x, p1y, p1z, n1} = 20 floats (80 B, 16B-aligned)
    __shared__ float tile[TSZ * 20];
    __shared__ float smem4[4];

    const float* f1n  = ws;
    const float* f2n  = ws + 16 * NPIX;
    const float* aux1 = ws + 32 * NPIX;
    const float* col2 = ws + 36 * NPIX;

    const int t = threadIdx.x;
    const int n = blockIdx.x * TSZ + t;   // column owned by this thread
    const int m0 = blockIdx.y * TSZ;      // row strip of this block

    // column-resident data in registers
    float f2r[CCH];
    #pragma unroll
    for (int cc = 0; cc < CCH; cc++) f2r[cc] = f2n[cc * NPIX + n];
    const float4 c0 = *(const float4*)(col2 + (size_t)n * 8);
    const float4 c1 = *(const float4*)(col2 + (size_t)n * 8 + 4);

    // stage row tile into LDS
    #pragma unroll
    for (int cc = 0; cc < CCH; cc++) tile[t * 20 + cc] = f1n[cc * NPIX + m0 + t];
    const float4 ax = *(const float4*)(aux1 + (size_t)(m0 + t) * 4);
    tile[t * 20 + 16] = ax.x;
    tile[t * 20 + 17] = ax.y;
    tile[t * 20 + 18] = ax.z;
    tile[t * 20 + 19] = ax.w;
    __syncthreads();

    const float NEGHALF_LOG2E = -0.5f;
    float acc = 0.0f;
    #pragma unroll 2
    for (int m = 0; m < TSZ; m++) {
        const float* row = &tile[m * 20];
        float dot = 0.0f;
        #pragma unroll
        for (int cc = 0; cc < CCH; cc++) dot = fmaf(row[cc], f2r[cc], dot);
        const float px = row[16], py = row[17], pz = row[18], n1 = row[19];

        float cr = px * c0.x;
        cr = fmaf(py, c0.y, cr);
        cr = fmaf(pz, c0.z, cr);
        float d2a = fmaf(-2.0f, cr, n1 + c0.w);
        d2a = fmaxf(d2a, 0.0f);
        const float e1 = __expf(NEGHALF_LOG2E * d2a);

        float crq = px * c1.x;
        crq = fmaf(py, c1.y, crq);
        crq = fmaf(pz, c1.z, crq);
        float d2b = fmaf(-2.0f, crq, n1 + c1.w);
        d2b = fmaxf(d2b, 0.0f);
        const float e2 = __expf(NEGHALF_LOG2E * d2b);

        acc = fmaf(e1 - e2, dot, acc);
    }

    float tot = block_reduce_256(acc, smem4);
    if (threadIdx.x == 0) {
        const float vcontrib = -tot * (1.0f / (float)NPIX);
        atomicAdd(out + 0, vcontrib);   // final_loss
        atomicAdd(out + 1, vcontrib);   // inner_neg
    }
}

extern "C" void kernel_launch(void* const* d_in, const int* in_sizes, int n_in,
                              void* d_out, int out_size, void* d_ws, size_t ws_size,
                              hipStream_t stream) {
    const float* feature1 = (const float*)d_in[0];
    const float* feature2 = (const float*)d_in[1];
    const float* depth1   = (const float*)d_in[2];
    const float* depth2   = (const float*)d_in[3];
    const float* pose1_2  = (const float*)d_in[4];
    const float* posenz   = (const float*)d_in[5];
    float* out = (float*)d_out;
    float* ws  = (float*)d_ws;

    // zero the three scalar accumulators (re-poisoned before every timed call)
    hipMemsetAsync(d_out, 0, (size_t)out_size * sizeof(float), stream);

    preproc_kernel<<<NBLK, 256, 0, stream>>>(feature1, feature2, depth1, depth2,
                                             pose1_2, posenz, ws, out);
    dim3 grid(NBLK, NBLK);
    pair_loss_kernel<<<grid, 256, 0, stream>>>(ws, out);
}